// Round 11
// baseline (41.754 us; speedup 1.0000x reference)
//
#include <hip/hip_runtime.h>
#include <hip/hip_bf16.h>

// B=1, NN=256, C=128, H=4, D=32 — O(N^3) factorization, 3 kernels.
//   k_w:  w = x @ W_w (256x512); also out = bias (for later atomics)
//   k_T:  P,Q,R on the fly; T = P R split along j into 4 quarters (T0..T3);
//         Q,P,Rt side-writes; normp partials. grid (8,8,16) = 1024 blocks,
//         4/CU. LDS row stride 38 (2-way bank aliasing only — free).
//   k_x1x2S: per block (4 rows, head h): rn; qs = Q*rn; S rows = qs @ Rt
//         (Rt read once per block, coalesced from L2 — NO LDS staging);
//         wp = P.*S, wq = qs.*(T0+..+T3); x1 = wp v, x2 = wq v; y = x1.*x2;
//         out += y @ W_proj[h-slice] (atomicAdd, bias-init by k_w).

constexpr size_t OFF_W     = 0;                     // 256*512
constexpr size_t OFF_P     = 131072;                // 4*65536
constexpr size_t OFF_Q     = OFF_P + 262144;
constexpr size_t OFF_RT    = OFF_Q + 262144;        // R^T: [h][k][j]
constexpr size_t OFF_T     = OFF_RT + 262144;       // four j-quarters: 4*262144
constexpr size_t OFF_NORMP = OFF_T + 1048576;       // 4*32*256 = 32768

// ---- K1: w = x(256x128) @ Ww(128x512), 32x32 tile, prefetch dbuf ----
__global__ __launch_bounds__(256) void k_w(const float* __restrict__ x,
                                           const float* __restrict__ Ww,
                                           float* __restrict__ w,
                                           const float* __restrict__ bp,
                                           float* __restrict__ out) {
    __shared__ __align__(16) float As[1152];  // [k][i]
    __shared__ __align__(16) float Bs[1152];  // [k][j]
    int j0 = blockIdx.x * 32, i0 = blockIdx.y * 32;
    int t = threadIdx.x, tx = t & 15, ty = t >> 4, r = t >> 3, g = t & 7;
    {   // bias-init out: 128 blocks * 256 threads == 32768 == out elements
        int oidx = (blockIdx.y * 16 + blockIdx.x) * 256 + t;
        out[oidx] = bp[oidx & 127];
    }
    float4 a4 = *(const float4*)&x[(size_t)(i0 + r) * 128 + g * 4];
    float4 b4 = *(const float4*)&Ww[(size_t)r * 512 + j0 + g * 4];
    float a00 = 0, a01 = 0, a10 = 0, a11 = 0;
    for (int kc = 0; kc < 128; kc += 32) {
        As[(g * 4 + 0) * 36 + r] = a4.x; As[(g * 4 + 1) * 36 + r] = a4.y;
        As[(g * 4 + 2) * 36 + r] = a4.z; As[(g * 4 + 3) * 36 + r] = a4.w;
        *(float4*)&Bs[r * 36 + g * 4] = b4;
        __syncthreads();
        if (kc + 32 < 128) {
            a4 = *(const float4*)&x[(size_t)(i0 + r) * 128 + kc + 32 + g * 4];
            b4 = *(const float4*)&Ww[(size_t)(kc + 32 + r) * 512 + j0 + g * 4];
        }
#pragma unroll
        for (int kk = 0; kk < 32; kk++) {
            float2 av = *(float2*)&As[kk * 36 + ty * 2];
            float2 bv = *(float2*)&Bs[kk * 36 + tx * 2];
            a00 += av.x * bv.x; a01 += av.x * bv.y;
            a10 += av.y * bv.x; a11 += av.y * bv.y;
        }
        __syncthreads();
    }
    *(float2*)&w[(size_t)(i0 + ty * 2) * 512 + j0 + tx * 2] = make_float2(a00, a01);
    *(float2*)&w[(size_t)(i0 + ty * 2 + 1) * 512 + j0 + tx * 2] = make_float2(a10, a11);
}

// ---- K2: fused PQR + T(j-quarter) + normp. grid (8, 8, 16): z = h*4+jq. ----
// LDS stride 38: staging-write bank pattern (24g+6X+r)%32 and transposed-store
// pattern (12tx+2ty)%32 are both period-8 in lane id -> 2-way aliasing (free).
__global__ __launch_bounds__(256, 2) void k_T(const float* __restrict__ w,
                                              float* __restrict__ P,
                                              float* __restrict__ Q,
                                              float* __restrict__ Rt,
                                              float* __restrict__ T,
                                              float* __restrict__ normp) {
    __shared__ __align__(16) float aT[1216];   // [d][i] stride 38
    __shared__ __align__(16) float cT[1216];   // [d][k] stride 38
    __shared__ __align__(16) float bT[1216];   // [d][j] stride 38
    __shared__ __align__(16) float PsT[1216];  // [i][j] stride 38
    __shared__ __align__(16) float RsT[1216];  // [k][j] stride 38
    int h = blockIdx.z >> 2, jq = blockIdx.z & 3;
    int k0 = blockIdx.x * 32, i0 = blockIdx.y * 32;
    int jc0 = jq * 64;
    size_t hb = (size_t)h * 65536;
    int t = threadIdx.x, tx = t & 15, ty = t >> 4, r = t >> 3, g = t & 7;
    const float sc = 0.17677669529663687f;

    float4 av = *(const float4*)&w[(size_t)(i0 + r) * 512 + h * 32 + g * 4];
    aT[(g * 4 + 0) * 38 + r] = av.x; aT[(g * 4 + 1) * 38 + r] = av.y;
    aT[(g * 4 + 2) * 38 + r] = av.z; aT[(g * 4 + 3) * 38 + r] = av.w;
    float4 cv = *(const float4*)&w[(size_t)(k0 + r) * 512 + 256 + h * 32 + g * 4];
    cT[(g * 4 + 0) * 38 + r] = cv.x; cT[(g * 4 + 1) * 38 + r] = cv.y;
    cT[(g * 4 + 2) * 38 + r] = cv.z; cT[(g * 4 + 3) * 38 + r] = cv.w;
    float4 bv = *(const float4*)&w[(size_t)(jc0 + r) * 512 + 128 + h * 32 + g * 4];
    __syncthreads();

    // register-cached fragments (static indices via full unroll)
    float2 a_tx[32], c_tx[32];
#pragma unroll
    for (int d = 0; d < 32; d++) {
        a_tx[d] = *(float2*)&aT[d * 38 + 2 * tx];
        c_tx[d] = *(float2*)&cT[d * 38 + 2 * tx];
    }

    // Q tile: i = 2ty+ii, k = 2tx+kk
    float dq00 = 0, dq01 = 0, dq10 = 0, dq11 = 0;
#pragma unroll
    for (int d = 0; d < 32; d++) {
        float2 a2 = *(float2*)&aT[d * 38 + 2 * ty];
        float2 c2 = c_tx[d];
        dq00 += a2.x * c2.x; dq01 += a2.x * c2.y;
        dq10 += a2.y * c2.x; dq11 += a2.y * c2.y;
    }
    float q00 = __expf(sc * dq00), q01 = __expf(sc * dq01);
    float q10 = __expf(sc * dq10), q11 = __expf(sc * dq11);
    if (jq == 0) {
        *(float2*)&Q[hb + (size_t)(i0 + ty * 2) * 256 + k0 + tx * 2] = make_float2(q00, q01);
        *(float2*)&Q[hb + (size_t)(i0 + ty * 2 + 1) * 256 + k0 + tx * 2] = make_float2(q10, q11);
    }

    const bool wP = (k0 == 0), wR = (blockIdx.y == 0);
    float acc00 = 0, acc01 = 0, acc10 = 0, acc11 = 0;
    for (int jc = jc0; jc < jc0 + 64; jc += 32) {
        bT[(g * 4 + 0) * 38 + r] = bv.x; bT[(g * 4 + 1) * 38 + r] = bv.y;
        bT[(g * 4 + 2) * 38 + r] = bv.z; bT[(g * 4 + 3) * 38 + r] = bv.w;
        __syncthreads();  // A: bT ready, prior PsT/RsT reads done
        if (jc + 32 < jc0 + 64)
            bv = *(const float4*)&w[(size_t)(jc + 32 + r) * 512 + 128 + h * 32 + g * 4];
        // P chunk: j = 2ty+jj, i = 2tx+ii ; R chunk: j = 2ty+jj, k = 2tx+kk
        float dp00 = 0, dp01 = 0, dp10 = 0, dp11 = 0;
        float dr00 = 0, dr01 = 0, dr10 = 0, dr11 = 0;
#pragma unroll
        for (int d = 0; d < 32; d++) {
            float2 b2 = *(float2*)&bT[d * 38 + 2 * ty];
            float2 a2 = a_tx[d];
            float2 c2 = c_tx[d];
            dp00 += b2.x * a2.x; dp01 += b2.x * a2.y;
            dp10 += b2.y * a2.x; dp11 += b2.y * a2.y;
            dr00 += b2.x * c2.x; dr01 += b2.x * c2.y;
            dr10 += b2.y * c2.x; dr11 += b2.y * c2.y;
        }
        float p00 = __expf(sc * dp00), p01 = __expf(sc * dp01);
        float p10 = __expf(sc * dp10), p11 = __expf(sc * dp11);
        float r00 = __expf(sc * dr00), r01 = __expf(sc * dr01);
        float r10 = __expf(sc * dr10), r11 = __expf(sc * dr11);
        // transposed stores: PsT[i][j], RsT[k][j]
        *(float2*)&PsT[(2 * tx + 0) * 38 + 2 * ty] = make_float2(p00, p10);
        *(float2*)&PsT[(2 * tx + 1) * 38 + 2 * ty] = make_float2(p01, p11);
        *(float2*)&RsT[(2 * tx + 0) * 38 + 2 * ty] = make_float2(r00, r10);
        *(float2*)&RsT[(2 * tx + 1) * 38 + 2 * ty] = make_float2(r01, r11);
        if (wP) {
            *(float2*)&P[hb + (size_t)(i0 + tx * 2 + 0) * 256 + jc + ty * 2] = make_float2(p00, p10);
            *(float2*)&P[hb + (size_t)(i0 + tx * 2 + 1) * 256 + jc + ty * 2] = make_float2(p01, p11);
        }
        if (wR) {
            *(float2*)&Rt[hb + (size_t)(k0 + tx * 2 + 0) * 256 + jc + ty * 2] = make_float2(r00, r10);
            *(float2*)&Rt[hb + (size_t)(k0 + tx * 2 + 1) * 256 + jc + ty * 2] = make_float2(r01, r11);
        }
        __syncthreads();  // B: PsT/RsT ready
        // T accumulate: dot along j in float4 quads
#pragma unroll
        for (int q = 0; q < 8; q++) {
            float4 pA = *(float4*)&PsT[(2 * ty + 0) * 38 + 4 * q];
            float4 pB = *(float4*)&PsT[(2 * ty + 1) * 38 + 4 * q];
            float4 rA = *(float4*)&RsT[(2 * tx + 0) * 38 + 4 * q];
            float4 rB = *(float4*)&RsT[(2 * tx + 1) * 38 + 4 * q];
            acc00 += pA.x * rA.x + pA.y * rA.y + pA.z * rA.z + pA.w * rA.w;
            acc01 += pA.x * rB.x + pA.y * rB.y + pA.z * rB.z + pA.w * rB.w;
            acc10 += pB.x * rA.x + pB.y * rA.y + pB.z * rA.z + pB.w * rA.w;
            acc11 += pB.x * rB.x + pB.y * rB.y + pB.z * rB.z + pB.w * rB.w;
        }
    }
    float* Tp = T + (size_t)jq * 262144;
    *(float2*)&Tp[hb + (size_t)(i0 + ty * 2) * 256 + k0 + tx * 2] = make_float2(acc00, acc01);
    *(float2*)&Tp[hb + (size_t)(i0 + ty * 2 + 1) * 256 + k0 + tx * 2] = make_float2(acc10, acc11);
    __syncthreads();
    float* red = PsT;  // [16][34]
    red[ty * 34 + tx * 2]     = q00 * acc00 + q10 * acc10;
    red[ty * 34 + tx * 2 + 1] = q01 * acc01 + q11 * acc11;
    __syncthreads();
    if (t < 32) {
        float s = 0.f;
#pragma unroll
        for (int m = 0; m < 16; m++) s += red[m * 34 + t];
        normp[h * 8192 + (jq * 8 + blockIdx.y) * 256 + k0 + t] = s;
    }
}

// ---- K3: S rows (from L2 Rt) + x1x2 + projection. grid (64, 4). ----
__global__ __launch_bounds__(256) void k_x1x2S(
    const float* __restrict__ P, const float* __restrict__ Q,
    const float* __restrict__ Rt, const float* __restrict__ T,
    const float* __restrict__ normp, const float* __restrict__ w,
    const float* __restrict__ Wp, float* __restrict__ out) {
    int h = blockIdx.y;
    int i0 = blockIdx.x * 4;
    size_t hb = (size_t)h * 65536;
    __shared__ float rn_s[256];
    __shared__ __align__(16) float qs[1024];   // [4][256] = Q*rn
    __shared__ __align__(16) float Ss[1024];   // [4][256] = S rows
    __shared__ __align__(16) float wp[1024];   // [4][256]; later redx
    __shared__ __align__(16) float wq[1024];   // [4][256]; later redy
    __shared__ __align__(16) float vT[8320];   // red[4][4][256] / [32][260] / Wps[32][128]
    __shared__ float ys[144];                  // [4][33+]
    int t = threadIdx.x;
    {
        float s = 0.f;
#pragma unroll
        for (int ib = 0; ib < 32; ib++) s += normp[h * 8192 + ib * 256 + t];
        rn_s[t] = 1.f / fmaxf(s, 1e-6f);
    }
    __syncthreads();
    {   // qs = Q rows * rn
        int row = t >> 6, jqc = (t & 63) * 4;
        float4 q4 = *(const float4*)&Q[hb + (size_t)(i0 + row) * 256 + jqc];
        float4 rn4 = *(float4*)&rn_s[jqc];
        q4.x *= rn4.x; q4.y *= rn4.y; q4.z *= rn4.z; q4.w *= rn4.w;
        *(float4*)&qs[row * 256 + jqc] = q4;
    }
    __syncthreads();
    // S partials: thread (jqc = t&63 float4-col, kq = t>>6 k-quarter)
    {
        int jqc = (t & 63) * 4, kq = t >> 6;
        float4 acc0 = {0, 0, 0, 0}, acc1 = {0, 0, 0, 0};
        float4 acc2 = {0, 0, 0, 0}, acc3 = {0, 0, 0, 0};
#pragma unroll 8
        for (int kk = 0; kk < 64; kk++) {
            int k = kq * 64 + kk;
            float4 r4 = *(const float4*)&Rt[hb + (size_t)k * 256 + jqc];
            float q0 = qs[0 * 256 + k], q1 = qs[1 * 256 + k];
            float q2 = qs[2 * 256 + k], q3 = qs[3 * 256 + k];
            acc0.x += q0 * r4.x; acc0.y += q0 * r4.y; acc0.z += q0 * r4.z; acc0.w += q0 * r4.w;
            acc1.x += q1 * r4.x; acc1.y += q1 * r4.y; acc1.z += q1 * r4.z; acc1.w += q1 * r4.w;
            acc2.x += q2 * r4.x; acc2.y += q2 * r4.y; acc2.z += q2 * r4.z; acc2.w += q2 * r4.w;
            acc3.x += q3 * r4.x; acc3.y += q3 * r4.y; acc3.z += q3 * r4.z; acc3.w += q3 * r4.w;
        }
        float* red = vT;  // red[kq][row][j]: 4*4*256 = 4096 floats
        *(float4*)&red[(kq * 4 + 0) * 256 + jqc] = acc0;
        *(float4*)&red[(kq * 4 + 1) * 256 + jqc] = acc1;
        *(float4*)&red[(kq * 4 + 2) * 256 + jqc] = acc2;
        *(float4*)&red[(kq * 4 + 3) * 256 + jqc] = acc3;
    }
    __syncthreads();
    {   // reduce 4 k-quarters -> Ss
        int row = t >> 6, jqc = (t & 63) * 4;
        float* red = vT;
        float4 s0 = *(float4*)&red[(0 * 4 + row) * 256 + jqc];
        float4 s1 = *(float4*)&red[(1 * 4 + row) * 256 + jqc];
        float4 s2 = *(float4*)&red[(2 * 4 + row) * 256 + jqc];
        float4 s3 = *(float4*)&red[(3 * 4 + row) * 256 + jqc];
        float4 sm;
        sm.x = (s0.x + s1.x) + (s2.x + s3.x);
        sm.y = (s0.y + s1.y) + (s2.y + s3.y);
        sm.z = (s0.z + s1.z) + (s2.z + s3.z);
        sm.w = (s0.w + s1.w) + (s2.w + s3.w);
        *(float4*)&Ss[row * 256 + jqc] = sm;
    }
    __syncthreads();  // red no longer needed; vT region free
#pragma unroll
    for (int m = 0; m < 8; m++) {  // stage vT[d][j] (transposed)
        int jj = m * 32 + (t >> 3);
        int dd = (t & 7) * 4;
        float4 v4 = *(const float4*)&w[(size_t)jj * 512 + 384 + h * 32 + dd];
        vT[(dd + 0) * 260 + jj] = v4.x;
        vT[(dd + 1) * 260 + jj] = v4.y;
        vT[(dd + 2) * 260 + jj] = v4.z;
        vT[(dd + 3) * 260 + jj] = v4.w;
    }
    {   // wp = P .* S ; wq = qs .* (T0+T1+T2+T3)
        int rr = t >> 6, jj = (t & 63) * 4;
        size_t o = hb + (size_t)(i0 + rr) * 256 + jj;
        float4 p4  = *(const float4*)&P[o];
        float4 t4a = *(const float4*)&T[o];
        float4 t4b = *(const float4*)&T[o + 262144];
        float4 t4c = *(const float4*)&T[o + 524288];
        float4 t4d = *(const float4*)&T[o + 786432];
        float4 q4  = *(float4*)&qs[rr * 256 + jj];
        float4 s4  = *(float4*)&Ss[rr * 256 + jj];
        float4 wpv, wqv;
        wpv.x = p4.x * s4.x; wpv.y = p4.y * s4.y;
        wpv.z = p4.z * s4.z; wpv.w = p4.w * s4.w;
        wqv.x = q4.x * ((t4a.x + t4b.x) + (t4c.x + t4d.x));
        wqv.y = q4.y * ((t4a.y + t4b.y) + (t4c.y + t4d.y));
        wqv.z = q4.z * ((t4a.z + t4b.z) + (t4c.z + t4d.z));
        wqv.w = q4.w * ((t4a.w + t4b.w) + (t4c.w + t4d.w));
        *(float4*)&wp[rr * 256 + jj] = wpv;
        *(float4*)&wq[rr * 256 + jj] = wqv;
    }
    __syncthreads();
    int d = t & 31, rl = (t >> 5) & 3, jh2 = t >> 7;
    int jbase = jh2 * 128;
    float x1 = 0.f, x2 = 0.f;
#pragma unroll
    for (int q = 0; q < 32; q++) {
        int j = jbase + 4 * q;
        float4 wp4 = *(float4*)&wp[rl * 256 + j];
        float4 wq4 = *(float4*)&wq[rl * 256 + j];
        float4 v4  = *(float4*)&vT[d * 260 + j];
        x1 += wp4.x * v4.x + wp4.y * v4.y + wp4.z * v4.z + wp4.w * v4.w;
        x2 += wq4.x * v4.x + wq4.y * v4.y + wq4.z * v4.z + wq4.w * v4.w;
    }
    __syncthreads();  // done reading wp/wq/vT
    float* redx = wp;
    float* redy = wq;
    redx[t] = x1;
    redy[t] = x2;
    float* Wps = vT;  // [32][128]
#pragma unroll
    for (int m = 0; m < 4; m++) {
        int idx = m * 256 + t;
        int k = idx >> 5, n = (idx & 31) * 4;
        *(float4*)&Wps[k * 128 + n] = *(const float4*)&Wp[(size_t)(h * 32 + k) * 128 + n];
    }
    __syncthreads();
    if (t < 128) {
        float x1t = redx[t] + redx[t + 128];
        float x2t = redy[t] + redy[t + 128];
        ys[rl * 33 + d] = x1t * x2t;   // rl = (t>>5)&3, d = t&31 with jh2==0
    }
    __syncthreads();
    int n = t & 127, ti = t >> 7;  // rows ti, ti+2
    float acc0 = 0.f, acc1 = 0.f;
#pragma unroll
    for (int k = 0; k < 32; k++) {
        float wv = Wps[k * 128 + n];
        acc0 += ys[(ti + 0) * 33 + k] * wv;
        acc1 += ys[(ti + 2) * 33 + k] * wv;
    }
    atomicAdd(&out[(size_t)(i0 + ti + 0) * 128 + n], acc0);
    atomicAdd(&out[(size_t)(i0 + ti + 2) * 128 + n], acc1);
}

extern "C" void kernel_launch(void* const* d_in, const int* in_sizes, int n_in,
                              void* d_out, int out_size, void* d_ws, size_t ws_size,
                              hipStream_t stream) {
    const float* x      = (const float*)d_in[0];
    const float* W_w    = (const float*)d_in[1];
    const float* W_proj = (const float*)d_in[2];
    const float* b_proj = (const float*)d_in[3];
    float* out = (float*)d_out;
    float* ws  = (float*)d_ws;

    float* w     = ws + OFF_W;
    float* P     = ws + OFF_P;
    float* Q     = ws + OFF_Q;
    float* Rt    = ws + OFF_RT;
    float* T     = ws + OFF_T;
    float* normp = ws + OFF_NORMP;

    k_w<<<dim3(16, 8), 256, 0, stream>>>(x, W_w, w, b_proj, out);
    k_T<<<dim3(8, 8, 16), 256, 0, stream>>>(w, P, Q, Rt, T, normp);
    k_x1x2S<<<dim3(64, 4), 256, 0, stream>>>(P, Q, Rt, T, normp, w, W_proj, out);
}

// Round 12
// 35.881 us; speedup vs baseline: 1.1637x; 1.1637x over previous
//
#include <hip/hip_runtime.h>
#include <hip/hip_bf16.h>

// B=1, NN=256, C=128, H=4, D=32 — O(N^3) factorization, 3 kernels.
//   k_w:  w = x @ W_w (256x512); also out = bias (for later atomics)
//   k_T:  P,Q,R on the fly; T = P R split along j into 2 halves (T0,T1);
//         Q,P,Rt side-writes; normp partials. 512 blocks, 2/CU.
//         LDS row stride 38 (2-way bank aliasing only — free; was 4-way @36).
//   k_x1x2S: per block (4 rows, head h): rn; qs = Q*rn; S rows = qs @ Rt
//         (Rt read once per block, coalesced from L2 — NO LDS staging);
//         wp = P.*S, wq = qs.*(T0+T1); x1 = wp v, x2 = wq v; y = x1.*x2;
//         out += y @ W_proj[h-slice] (atomicAdd, bias-init by k_w).

constexpr size_t OFF_W     = 0;                     // 256*512
constexpr size_t OFF_P     = 131072;                // 4*65536
constexpr size_t OFF_Q     = OFF_P + 262144;
constexpr size_t OFF_RT    = OFF_Q + 262144;        // R^T: [h][k][j]
constexpr size_t OFF_T     = OFF_RT + 262144;       // two j-halves: 2*262144
constexpr size_t OFF_NORMP = OFF_T + 524288;        // 4*16*256 = 16384

// ---- K1: w = x(256x128) @ Ww(128x512), 32x32 tile, prefetch dbuf ----
__global__ __launch_bounds__(256) void k_w(const float* __restrict__ x,
                                           const float* __restrict__ Ww,
                                           float* __restrict__ w,
                                           const float* __restrict__ bp,
                                           float* __restrict__ out) {
    __shared__ __align__(16) float As[1152];  // [k][i]
    __shared__ __align__(16) float Bs[1152];  // [k][j]
    int j0 = blockIdx.x * 32, i0 = blockIdx.y * 32;
    int t = threadIdx.x, tx = t & 15, ty = t >> 4, r = t >> 3, g = t & 7;
    {   // bias-init out: 128 blocks * 256 threads == 32768 == out elements
        int oidx = (blockIdx.y * 16 + blockIdx.x) * 256 + t;
        out[oidx] = bp[oidx & 127];
    }
    float4 a4 = *(const float4*)&x[(size_t)(i0 + r) * 128 + g * 4];
    float4 b4 = *(const float4*)&Ww[(size_t)r * 512 + j0 + g * 4];
    float a00 = 0, a01 = 0, a10 = 0, a11 = 0;
    for (int kc = 0; kc < 128; kc += 32) {
        As[(g * 4 + 0) * 36 + r] = a4.x; As[(g * 4 + 1) * 36 + r] = a4.y;
        As[(g * 4 + 2) * 36 + r] = a4.z; As[(g * 4 + 3) * 36 + r] = a4.w;
        *(float4*)&Bs[r * 36 + g * 4] = b4;
        __syncthreads();
        if (kc + 32 < 128) {
            a4 = *(const float4*)&x[(size_t)(i0 + r) * 128 + kc + 32 + g * 4];
            b4 = *(const float4*)&Ww[(size_t)(kc + 32 + r) * 512 + j0 + g * 4];
        }
#pragma unroll
        for (int kk = 0; kk < 32; kk++) {
            float2 av = *(float2*)&As[kk * 36 + ty * 2];
            float2 bv = *(float2*)&Bs[kk * 36 + tx * 2];
            a00 += av.x * bv.x; a01 += av.x * bv.y;
            a10 += av.y * bv.x; a11 += av.y * bv.y;
        }
        __syncthreads();
    }
    *(float2*)&w[(size_t)(i0 + ty * 2) * 512 + j0 + tx * 2] = make_float2(a00, a01);
    *(float2*)&w[(size_t)(i0 + ty * 2 + 1) * 512 + j0 + tx * 2] = make_float2(a10, a11);
}

// ---- K2: fused PQR + T(j-half) + normp. grid (8, 8, 8): z = h*2+jh. ----
// LDS row stride 38: staging-write pattern (24g+6X+r)%32 and transposed-store
// pattern (12tx+2ty)%32 are period-8 in lane id -> 2-way aliasing (free).
__global__ __launch_bounds__(256, 2) void k_T(const float* __restrict__ w,
                                              float* __restrict__ P,
                                              float* __restrict__ Q,
                                              float* __restrict__ Rt,
                                              float* __restrict__ T,
                                              float* __restrict__ normp) {
    __shared__ __align__(16) float aT[1216];   // [d][i] stride 38
    __shared__ __align__(16) float cT[1216];   // [d][k] stride 38
    __shared__ __align__(16) float bT[1216];   // [d][j] stride 38
    __shared__ __align__(16) float PsT[1216];  // [i][j] stride 38
    __shared__ __align__(16) float RsT[1216];  // [k][j] stride 38
    int h = blockIdx.z >> 1, jh = blockIdx.z & 1;
    int k0 = blockIdx.x * 32, i0 = blockIdx.y * 32;
    int jc0 = jh * 128;
    size_t hb = (size_t)h * 65536;
    int t = threadIdx.x, tx = t & 15, ty = t >> 4, r = t >> 3, g = t & 7;
    const float sc = 0.17677669529663687f;

    float4 av = *(const float4*)&w[(size_t)(i0 + r) * 512 + h * 32 + g * 4];
    aT[(g * 4 + 0) * 38 + r] = av.x; aT[(g * 4 + 1) * 38 + r] = av.y;
    aT[(g * 4 + 2) * 38 + r] = av.z; aT[(g * 4 + 3) * 38 + r] = av.w;
    float4 cv = *(const float4*)&w[(size_t)(k0 + r) * 512 + 256 + h * 32 + g * 4];
    cT[(g * 4 + 0) * 38 + r] = cv.x; cT[(g * 4 + 1) * 38 + r] = cv.y;
    cT[(g * 4 + 2) * 38 + r] = cv.z; cT[(g * 4 + 3) * 38 + r] = cv.w;
    float4 bv = *(const float4*)&w[(size_t)(jc0 + r) * 512 + 128 + h * 32 + g * 4];
    __syncthreads();

    // register-cached fragments (static indices via full unroll)
    float2 a_tx[32], c_tx[32];
#pragma unroll
    for (int d = 0; d < 32; d++) {
        a_tx[d] = *(float2*)&aT[d * 38 + 2 * tx];
        c_tx[d] = *(float2*)&cT[d * 38 + 2 * tx];
    }

    // Q tile: i = 2ty+ii, k = 2tx+kk
    float dq00 = 0, dq01 = 0, dq10 = 0, dq11 = 0;
#pragma unroll
    for (int d = 0; d < 32; d++) {
        float2 a2 = *(float2*)&aT[d * 38 + 2 * ty];
        float2 c2 = c_tx[d];
        dq00 += a2.x * c2.x; dq01 += a2.x * c2.y;
        dq10 += a2.y * c2.x; dq11 += a2.y * c2.y;
    }
    float q00 = __expf(sc * dq00), q01 = __expf(sc * dq01);
    float q10 = __expf(sc * dq10), q11 = __expf(sc * dq11);
    if (jh == 0) {
        *(float2*)&Q[hb + (size_t)(i0 + ty * 2) * 256 + k0 + tx * 2] = make_float2(q00, q01);
        *(float2*)&Q[hb + (size_t)(i0 + ty * 2 + 1) * 256 + k0 + tx * 2] = make_float2(q10, q11);
    }

    const bool wP = (k0 == 0), wR = (blockIdx.y == 0);
    float acc00 = 0, acc01 = 0, acc10 = 0, acc11 = 0;
    for (int jc = jc0; jc < jc0 + 128; jc += 32) {
        bT[(g * 4 + 0) * 38 + r] = bv.x; bT[(g * 4 + 1) * 38 + r] = bv.y;
        bT[(g * 4 + 2) * 38 + r] = bv.z; bT[(g * 4 + 3) * 38 + r] = bv.w;
        __syncthreads();  // A: bT ready, prior PsT/RsT reads done
        if (jc + 32 < jc0 + 128)
            bv = *(const float4*)&w[(size_t)(jc + 32 + r) * 512 + 128 + h * 32 + g * 4];
        // P chunk: j = 2ty+jj, i = 2tx+ii ; R chunk: j = 2ty+jj, k = 2tx+kk
        float dp00 = 0, dp01 = 0, dp10 = 0, dp11 = 0;
        float dr00 = 0, dr01 = 0, dr10 = 0, dr11 = 0;
#pragma unroll
        for (int d = 0; d < 32; d++) {
            float2 b2 = *(float2*)&bT[d * 38 + 2 * ty];
            float2 a2 = a_tx[d];
            float2 c2 = c_tx[d];
            dp00 += b2.x * a2.x; dp01 += b2.x * a2.y;
            dp10 += b2.y * a2.x; dp11 += b2.y * a2.y;
            dr00 += b2.x * c2.x; dr01 += b2.x * c2.y;
            dr10 += b2.y * c2.x; dr11 += b2.y * c2.y;
        }
        float p00 = __expf(sc * dp00), p01 = __expf(sc * dp01);
        float p10 = __expf(sc * dp10), p11 = __expf(sc * dp11);
        float r00 = __expf(sc * dr00), r01 = __expf(sc * dr01);
        float r10 = __expf(sc * dr10), r11 = __expf(sc * dr11);
        // transposed stores: PsT[i][j], RsT[k][j]
        *(float2*)&PsT[(2 * tx + 0) * 38 + 2 * ty] = make_float2(p00, p10);
        *(float2*)&PsT[(2 * tx + 1) * 38 + 2 * ty] = make_float2(p01, p11);
        *(float2*)&RsT[(2 * tx + 0) * 38 + 2 * ty] = make_float2(r00, r10);
        *(float2*)&RsT[(2 * tx + 1) * 38 + 2 * ty] = make_float2(r01, r11);
        if (wP) {
            *(float2*)&P[hb + (size_t)(i0 + tx * 2 + 0) * 256 + jc + ty * 2] = make_float2(p00, p10);
            *(float2*)&P[hb + (size_t)(i0 + tx * 2 + 1) * 256 + jc + ty * 2] = make_float2(p01, p11);
        }
        if (wR) {
            *(float2*)&Rt[hb + (size_t)(k0 + tx * 2 + 0) * 256 + jc + ty * 2] = make_float2(r00, r10);
            *(float2*)&Rt[hb + (size_t)(k0 + tx * 2 + 1) * 256 + jc + ty * 2] = make_float2(r01, r11);
        }
        __syncthreads();  // B: PsT/RsT ready
        // T accumulate: dot along j in float4 quads
#pragma unroll
        for (int q = 0; q < 8; q++) {
            float4 pA = *(float4*)&PsT[(2 * ty + 0) * 38 + 4 * q];
            float4 pB = *(float4*)&PsT[(2 * ty + 1) * 38 + 4 * q];
            float4 rA = *(float4*)&RsT[(2 * tx + 0) * 38 + 4 * q];
            float4 rB = *(float4*)&RsT[(2 * tx + 1) * 38 + 4 * q];
            acc00 += pA.x * rA.x + pA.y * rA.y + pA.z * rA.z + pA.w * rA.w;
            acc01 += pA.x * rB.x + pA.y * rB.y + pA.z * rB.z + pA.w * rB.w;
            acc10 += pB.x * rA.x + pB.y * rA.y + pB.z * rA.z + pB.w * rA.w;
            acc11 += pB.x * rB.x + pB.y * rB.y + pB.z * rB.z + pB.w * rB.w;
        }
    }
    float* Tp = T + (size_t)jh * 262144;
    *(float2*)&Tp[hb + (size_t)(i0 + ty * 2) * 256 + k0 + tx * 2] = make_float2(acc00, acc01);
    *(float2*)&Tp[hb + (size_t)(i0 + ty * 2 + 1) * 256 + k0 + tx * 2] = make_float2(acc10, acc11);
    __syncthreads();
    float* red = PsT;  // [16][34]
    red[ty * 34 + tx * 2]     = q00 * acc00 + q10 * acc10;
    red[ty * 34 + tx * 2 + 1] = q01 * acc01 + q11 * acc11;
    __syncthreads();
    if (t < 32) {
        float s = 0.f;
#pragma unroll
        for (int m = 0; m < 16; m++) s += red[m * 34 + t];
        normp[h * 4096 + (jh * 8 + blockIdx.y) * 256 + k0 + t] = s;
    }
}

// ---- K3: S rows (from L2 Rt) + x1x2 + projection. grid (64, 4). ----
__global__ __launch_bounds__(256) void k_x1x2S(
    const float* __restrict__ P, const float* __restrict__ Q,
    const float* __restrict__ Rt, const float* __restrict__ T,
    const float* __restrict__ normp, const float* __restrict__ w,
    const float* __restrict__ Wp, float* __restrict__ out) {
    int h = blockIdx.y;
    int i0 = blockIdx.x * 4;
    size_t hb = (size_t)h * 65536;
    __shared__ float rn_s[256];
    __shared__ __align__(16) float qs[1024];   // [4][256] = Q*rn
    __shared__ __align__(16) float Ss[1024];   // [4][256] = S rows
    __shared__ __align__(16) float wp[1024];   // [4][256]; later redx
    __shared__ __align__(16) float wq[1024];   // [4][256]; later redy
    __shared__ __align__(16) float vT[8320];   // red[4][4][256] / [32][260] / Wps[32][128]
    __shared__ float ys[144];                  // [4][33+]
    int t = threadIdx.x;
    {
        float s = 0.f;
#pragma unroll
        for (int ib = 0; ib < 16; ib++) s += normp[h * 4096 + ib * 256 + t];
        rn_s[t] = 1.f / fmaxf(s, 1e-6f);
    }
    __syncthreads();
    {   // qs = Q rows * rn
        int row = t >> 6, jqc = (t & 63) * 4;
        float4 q4 = *(const float4*)&Q[hb + (size_t)(i0 + row) * 256 + jqc];
        float4 rn4 = *(float4*)&rn_s[jqc];
        q4.x *= rn4.x; q4.y *= rn4.y; q4.z *= rn4.z; q4.w *= rn4.w;
        *(float4*)&qs[row * 256 + jqc] = q4;
    }
    __syncthreads();
    // S partials: thread (jqc = t&63 float4-col, kq = t>>6 k-quarter)
    {
        int jqc = (t & 63) * 4, kq = t >> 6;
        float4 acc0 = {0, 0, 0, 0}, acc1 = {0, 0, 0, 0};
        float4 acc2 = {0, 0, 0, 0}, acc3 = {0, 0, 0, 0};
#pragma unroll 8
        for (int kk = 0; kk < 64; kk++) {
            int k = kq * 64 + kk;
            float4 r4 = *(const float4*)&Rt[hb + (size_t)k * 256 + jqc];
            float q0 = qs[0 * 256 + k], q1 = qs[1 * 256 + k];
            float q2 = qs[2 * 256 + k], q3 = qs[3 * 256 + k];
            acc0.x += q0 * r4.x; acc0.y += q0 * r4.y; acc0.z += q0 * r4.z; acc0.w += q0 * r4.w;
            acc1.x += q1 * r4.x; acc1.y += q1 * r4.y; acc1.z += q1 * r4.z; acc1.w += q1 * r4.w;
            acc2.x += q2 * r4.x; acc2.y += q2 * r4.y; acc2.z += q2 * r4.z; acc2.w += q2 * r4.w;
            acc3.x += q3 * r4.x; acc3.y += q3 * r4.y; acc3.z += q3 * r4.z; acc3.w += q3 * r4.w;
        }
        float* red = vT;  // red[kq][row][j]: 4*4*256 = 4096 floats
        *(float4*)&red[(kq * 4 + 0) * 256 + jqc] = acc0;
        *(float4*)&red[(kq * 4 + 1) * 256 + jqc] = acc1;
        *(float4*)&red[(kq * 4 + 2) * 256 + jqc] = acc2;
        *(float4*)&red[(kq * 4 + 3) * 256 + jqc] = acc3;
    }
    __syncthreads();
    {   // reduce 4 k-quarters -> Ss
        int row = t >> 6, jqc = (t & 63) * 4;
        float* red = vT;
        float4 s0 = *(float4*)&red[(0 * 4 + row) * 256 + jqc];
        float4 s1 = *(float4*)&red[(1 * 4 + row) * 256 + jqc];
        float4 s2 = *(float4*)&red[(2 * 4 + row) * 256 + jqc];
        float4 s3 = *(float4*)&red[(3 * 4 + row) * 256 + jqc];
        float4 sm;
        sm.x = (s0.x + s1.x) + (s2.x + s3.x);
        sm.y = (s0.y + s1.y) + (s2.y + s3.y);
        sm.z = (s0.z + s1.z) + (s2.z + s3.z);
        sm.w = (s0.w + s1.w) + (s2.w + s3.w);
        *(float4*)&Ss[row * 256 + jqc] = sm;
    }
    __syncthreads();  // red no longer needed; vT region free
#pragma unroll
    for (int m = 0; m < 8; m++) {  // stage vT[d][j] (transposed)
        int jj = m * 32 + (t >> 3);
        int dd = (t & 7) * 4;
        float4 v4 = *(const float4*)&w[(size_t)jj * 512 + 384 + h * 32 + dd];
        vT[(dd + 0) * 260 + jj] = v4.x;
        vT[(dd + 1) * 260 + jj] = v4.y;
        vT[(dd + 2) * 260 + jj] = v4.z;
        vT[(dd + 3) * 260 + jj] = v4.w;
    }
    {   // wp = P .* S ; wq = qs .* (T0+T1)
        int rr = t >> 6, jj = (t & 63) * 4;
        size_t o = hb + (size_t)(i0 + rr) * 256 + jj;
        float4 p4  = *(const float4*)&P[o];
        float4 t4a = *(const float4*)&T[o];
        float4 t4b = *(const float4*)&T[o + 262144];
        float4 q4  = *(float4*)&qs[rr * 256 + jj];
        float4 s4  = *(float4*)&Ss[rr * 256 + jj];
        float4 wpv, wqv;
        wpv.x = p4.x * s4.x; wpv.y = p4.y * s4.y;
        wpv.z = p4.z * s4.z; wpv.w = p4.w * s4.w;
        wqv.x = q4.x * (t4a.x + t4b.x); wqv.y = q4.y * (t4a.y + t4b.y);
        wqv.z = q4.z * (t4a.z + t4b.z); wqv.w = q4.w * (t4a.w + t4b.w);
        *(float4*)&wp[rr * 256 + jj] = wpv;
        *(float4*)&wq[rr * 256 + jj] = wqv;
    }
    __syncthreads();
    int d = t & 31, rl = (t >> 5) & 3, jh2 = t >> 7;
    int jbase = jh2 * 128;
    float x1 = 0.f, x2 = 0.f;
#pragma unroll
    for (int q = 0; q < 32; q++) {
        int j = jbase + 4 * q;
        float4 wp4 = *(float4*)&wp[rl * 256 + j];
        float4 wq4 = *(float4*)&wq[rl * 256 + j];
        float4 v4  = *(float4*)&vT[d * 260 + j];
        x1 += wp4.x * v4.x + wp4.y * v4.y + wp4.z * v4.z + wp4.w * v4.w;
        x2 += wq4.x * v4.x + wq4.y * v4.y + wq4.z * v4.z + wq4.w * v4.w;
    }
    __syncthreads();  // done reading wp/wq/vT
    float* redx = wp;
    float* redy = wq;
    redx[t] = x1;
    redy[t] = x2;
    float* Wps = vT;  // [32][128]
#pragma unroll
    for (int m = 0; m < 4; m++) {
        int idx = m * 256 + t;
        int k = idx >> 5, n = (idx & 31) * 4;
        *(float4*)&Wps[k * 128 + n] = *(const float4*)&Wp[(size_t)(h * 32 + k) * 128 + n];
    }
    __syncthreads();
    if (t < 128) {
        float x1t = redx[t] + redx[t + 128];
        float x2t = redy[t] + redy[t + 128];
        ys[rl * 33 + d] = x1t * x2t;   // rl = (t>>5)&3, d = t&31 with jh2==0
    }
    __syncthreads();
    int n = t & 127, ti = t >> 7;  // rows ti, ti+2
    float acc0 = 0.f, acc1 = 0.f;
#pragma unroll
    for (int k = 0; k < 32; k++) {
        float wv = Wps[k * 128 + n];
        acc0 += ys[(ti + 0) * 33 + k] * wv;
        acc1 += ys[(ti + 2) * 33 + k] * wv;
    }
    atomicAdd(&out[(size_t)(i0 + ti + 0) * 128 + n], acc0);
    atomicAdd(&out[(size_t)(i0 + ti + 2) * 128 + n], acc1);
}

extern "C" void kernel_launch(void* const* d_in, const int* in_sizes, int n_in,
                              void* d_out, int out_size, void* d_ws, size_t ws_size,
                              hipStream_t stream) {
    const float* x      = (const float*)d_in[0];
    const float* W_w    = (const float*)d_in[1];
    const float* W_proj = (const float*)d_in[2];
    const float* b_proj = (const float*)d_in[3];
    float* out = (float*)d_out;
    float* ws  = (float*)d_ws;

    float* w     = ws + OFF_W;
    float* P     = ws + OFF_P;
    float* Q     = ws + OFF_Q;
    float* Rt    = ws + OFF_RT;
    float* T     = ws + OFF_T;
    float* normp = ws + OFF_NORMP;

    k_w<<<dim3(16, 8), 256, 0, stream>>>(x, W_w, w, b_proj, out);
    k_T<<<dim3(8, 8, 8), 256, 0, stream>>>(w, P, Q, Rt, T, normp);
    k_x1x2S<<<dim3(64, 4), 256, 0, stream>>>(P, Q, Rt, T, normp, w, W_proj, out);
}

// Round 13
// 35.251 us; speedup vs baseline: 1.1845x; 1.0179x over previous
//
#include <hip/hip_runtime.h>
#include <hip/hip_bf16.h>

// B=1, NN=256, C=128, H=4, D=32 — O(N^3) factorization, 3 kernels.
//   k_w:  w = x @ W_w (256x512); also out = bias (for later atomics)
//   k_T:  P,Q,R on the fly; T = P R split along j into 2 halves (T0,T1);
//         Q,P,Rt side-writes; normp partials. 512 blocks, 2/CU.
//         LDS row stride 38 (2-way bank aliasing only — free).
//   k_x1x2S: 512 threads/block (2 waves/SIMD for latency hiding).
//         per block (4 rows, head h): rn; qs = Q*rn; S rows = qs @ Rt
//         (Rt read once per block, coalesced from L2 — NO LDS staging);
//         wp = P.*S, wq = qs.*(T0+T1); x1 = wp v, x2 = wq v; y = x1.*x2;
//         out += y @ W_proj[h-slice] (atomicAdd, bias-init by k_w).

constexpr size_t OFF_W     = 0;                     // 256*512
constexpr size_t OFF_P     = 131072;                // 4*65536
constexpr size_t OFF_Q     = OFF_P + 262144;
constexpr size_t OFF_RT    = OFF_Q + 262144;        // R^T: [h][k][j]
constexpr size_t OFF_T     = OFF_RT + 262144;       // two j-halves: 2*262144
constexpr size_t OFF_NORMP = OFF_T + 524288;        // 4*16*256 = 16384

// ---- K1: w = x(256x128) @ Ww(128x512), 32x32 tile, prefetch dbuf ----
__global__ __launch_bounds__(256) void k_w(const float* __restrict__ x,
                                           const float* __restrict__ Ww,
                                           float* __restrict__ w,
                                           const float* __restrict__ bp,
                                           float* __restrict__ out) {
    __shared__ __align__(16) float As[1152];  // [k][i]
    __shared__ __align__(16) float Bs[1152];  // [k][j]
    int j0 = blockIdx.x * 32, i0 = blockIdx.y * 32;
    int t = threadIdx.x, tx = t & 15, ty = t >> 4, r = t >> 3, g = t & 7;
    {   // bias-init out: 128 blocks * 256 threads == 32768 == out elements
        int oidx = (blockIdx.y * 16 + blockIdx.x) * 256 + t;
        out[oidx] = bp[oidx & 127];
    }
    float4 a4 = *(const float4*)&x[(size_t)(i0 + r) * 128 + g * 4];
    float4 b4 = *(const float4*)&Ww[(size_t)r * 512 + j0 + g * 4];
    float a00 = 0, a01 = 0, a10 = 0, a11 = 0;
    for (int kc = 0; kc < 128; kc += 32) {
        As[(g * 4 + 0) * 36 + r] = a4.x; As[(g * 4 + 1) * 36 + r] = a4.y;
        As[(g * 4 + 2) * 36 + r] = a4.z; As[(g * 4 + 3) * 36 + r] = a4.w;
        *(float4*)&Bs[r * 36 + g * 4] = b4;
        __syncthreads();
        if (kc + 32 < 128) {
            a4 = *(const float4*)&x[(size_t)(i0 + r) * 128 + kc + 32 + g * 4];
            b4 = *(const float4*)&Ww[(size_t)(kc + 32 + r) * 512 + j0 + g * 4];
        }
#pragma unroll
        for (int kk = 0; kk < 32; kk++) {
            float2 av = *(float2*)&As[kk * 36 + ty * 2];
            float2 bv = *(float2*)&Bs[kk * 36 + tx * 2];
            a00 += av.x * bv.x; a01 += av.x * bv.y;
            a10 += av.y * bv.x; a11 += av.y * bv.y;
        }
        __syncthreads();
    }
    *(float2*)&w[(size_t)(i0 + ty * 2) * 512 + j0 + tx * 2] = make_float2(a00, a01);
    *(float2*)&w[(size_t)(i0 + ty * 2 + 1) * 512 + j0 + tx * 2] = make_float2(a10, a11);
}

// ---- K2: fused PQR + T(j-half) + normp. grid (8, 8, 8): z = h*2+jh. ----
__global__ __launch_bounds__(256, 2) void k_T(const float* __restrict__ w,
                                              float* __restrict__ P,
                                              float* __restrict__ Q,
                                              float* __restrict__ Rt,
                                              float* __restrict__ T,
                                              float* __restrict__ normp) {
    __shared__ __align__(16) float aT[1216];   // [d][i] stride 38
    __shared__ __align__(16) float cT[1216];   // [d][k] stride 38
    __shared__ __align__(16) float bT[1216];   // [d][j] stride 38
    __shared__ __align__(16) float PsT[1216];  // [i][j] stride 38
    __shared__ __align__(16) float RsT[1216];  // [k][j] stride 38
    int h = blockIdx.z >> 1, jh = blockIdx.z & 1;
    int k0 = blockIdx.x * 32, i0 = blockIdx.y * 32;
    int jc0 = jh * 128;
    size_t hb = (size_t)h * 65536;
    int t = threadIdx.x, tx = t & 15, ty = t >> 4, r = t >> 3, g = t & 7;
    const float sc = 0.17677669529663687f;

    float4 av = *(const float4*)&w[(size_t)(i0 + r) * 512 + h * 32 + g * 4];
    aT[(g * 4 + 0) * 38 + r] = av.x; aT[(g * 4 + 1) * 38 + r] = av.y;
    aT[(g * 4 + 2) * 38 + r] = av.z; aT[(g * 4 + 3) * 38 + r] = av.w;
    float4 cv = *(const float4*)&w[(size_t)(k0 + r) * 512 + 256 + h * 32 + g * 4];
    cT[(g * 4 + 0) * 38 + r] = cv.x; cT[(g * 4 + 1) * 38 + r] = cv.y;
    cT[(g * 4 + 2) * 38 + r] = cv.z; cT[(g * 4 + 3) * 38 + r] = cv.w;
    float4 bv = *(const float4*)&w[(size_t)(jc0 + r) * 512 + 128 + h * 32 + g * 4];
    __syncthreads();

    float2 a_tx[32], c_tx[32];
#pragma unroll
    for (int d = 0; d < 32; d++) {
        a_tx[d] = *(float2*)&aT[d * 38 + 2 * tx];
        c_tx[d] = *(float2*)&cT[d * 38 + 2 * tx];
    }

    float dq00 = 0, dq01 = 0, dq10 = 0, dq11 = 0;
#pragma unroll
    for (int d = 0; d < 32; d++) {
        float2 a2 = *(float2*)&aT[d * 38 + 2 * ty];
        float2 c2 = c_tx[d];
        dq00 += a2.x * c2.x; dq01 += a2.x * c2.y;
        dq10 += a2.y * c2.x; dq11 += a2.y * c2.y;
    }
    float q00 = __expf(sc * dq00), q01 = __expf(sc * dq01);
    float q10 = __expf(sc * dq10), q11 = __expf(sc * dq11);
    if (jh == 0) {
        *(float2*)&Q[hb + (size_t)(i0 + ty * 2) * 256 + k0 + tx * 2] = make_float2(q00, q01);
        *(float2*)&Q[hb + (size_t)(i0 + ty * 2 + 1) * 256 + k0 + tx * 2] = make_float2(q10, q11);
    }

    const bool wP = (k0 == 0), wR = (blockIdx.y == 0);
    float acc00 = 0, acc01 = 0, acc10 = 0, acc11 = 0;
    for (int jc = jc0; jc < jc0 + 128; jc += 32) {
        bT[(g * 4 + 0) * 38 + r] = bv.x; bT[(g * 4 + 1) * 38 + r] = bv.y;
        bT[(g * 4 + 2) * 38 + r] = bv.z; bT[(g * 4 + 3) * 38 + r] = bv.w;
        __syncthreads();  // A: bT ready, prior PsT/RsT reads done
        if (jc + 32 < jc0 + 128)
            bv = *(const float4*)&w[(size_t)(jc + 32 + r) * 512 + 128 + h * 32 + g * 4];
        float dp00 = 0, dp01 = 0, dp10 = 0, dp11 = 0;
        float dr00 = 0, dr01 = 0, dr10 = 0, dr11 = 0;
#pragma unroll
        for (int d = 0; d < 32; d++) {
            float2 b2 = *(float2*)&bT[d * 38 + 2 * ty];
            float2 a2 = a_tx[d];
            float2 c2 = c_tx[d];
            dp00 += b2.x * a2.x; dp01 += b2.x * a2.y;
            dp10 += b2.y * a2.x; dp11 += b2.y * a2.y;
            dr00 += b2.x * c2.x; dr01 += b2.x * c2.y;
            dr10 += b2.y * c2.x; dr11 += b2.y * c2.y;
        }
        float p00 = __expf(sc * dp00), p01 = __expf(sc * dp01);
        float p10 = __expf(sc * dp10), p11 = __expf(sc * dp11);
        float r00 = __expf(sc * dr00), r01 = __expf(sc * dr01);
        float r10 = __expf(sc * dr10), r11 = __expf(sc * dr11);
        *(float2*)&PsT[(2 * tx + 0) * 38 + 2 * ty] = make_float2(p00, p10);
        *(float2*)&PsT[(2 * tx + 1) * 38 + 2 * ty] = make_float2(p01, p11);
        *(float2*)&RsT[(2 * tx + 0) * 38 + 2 * ty] = make_float2(r00, r10);
        *(float2*)&RsT[(2 * tx + 1) * 38 + 2 * ty] = make_float2(r01, r11);
        if (wP) {
            *(float2*)&P[hb + (size_t)(i0 + tx * 2 + 0) * 256 + jc + ty * 2] = make_float2(p00, p10);
            *(float2*)&P[hb + (size_t)(i0 + tx * 2 + 1) * 256 + jc + ty * 2] = make_float2(p01, p11);
        }
        if (wR) {
            *(float2*)&Rt[hb + (size_t)(k0 + tx * 2 + 0) * 256 + jc + ty * 2] = make_float2(r00, r10);
            *(float2*)&Rt[hb + (size_t)(k0 + tx * 2 + 1) * 256 + jc + ty * 2] = make_float2(r01, r11);
        }
        __syncthreads();  // B: PsT/RsT ready
#pragma unroll
        for (int q = 0; q < 8; q++) {
            float4 pA = *(float4*)&PsT[(2 * ty + 0) * 38 + 4 * q];
            float4 pB = *(float4*)&PsT[(2 * ty + 1) * 38 + 4 * q];
            float4 rA = *(float4*)&RsT[(2 * tx + 0) * 38 + 4 * q];
            float4 rB = *(float4*)&RsT[(2 * tx + 1) * 38 + 4 * q];
            acc00 += pA.x * rA.x + pA.y * rA.y + pA.z * rA.z + pA.w * rA.w;
            acc01 += pA.x * rB.x + pA.y * rB.y + pA.z * rB.z + pA.w * rB.w;
            acc10 += pB.x * rA.x + pB.y * rA.y + pB.z * rA.z + pB.w * rA.w;
            acc11 += pB.x * rB.x + pB.y * rB.y + pB.z * rB.z + pB.w * rB.w;
        }
    }
    float* Tp = T + (size_t)jh * 262144;
    *(float2*)&Tp[hb + (size_t)(i0 + ty * 2) * 256 + k0 + tx * 2] = make_float2(acc00, acc01);
    *(float2*)&Tp[hb + (size_t)(i0 + ty * 2 + 1) * 256 + k0 + tx * 2] = make_float2(acc10, acc11);
    __syncthreads();
    float* red = PsT;  // [16][34]
    red[ty * 34 + tx * 2]     = q00 * acc00 + q10 * acc10;
    red[ty * 34 + tx * 2 + 1] = q01 * acc01 + q11 * acc11;
    __syncthreads();
    if (t < 32) {
        float s = 0.f;
#pragma unroll
        for (int m = 0; m < 16; m++) s += red[m * 34 + t];
        normp[h * 4096 + (jh * 8 + blockIdx.y) * 256 + k0 + t] = s;
    }
}

// ---- K3: S rows (from L2 Rt) + x1x2 + projection. grid (64, 4), 512 thr. ----
__global__ __launch_bounds__(512) void k_x1x2S(
    const float* __restrict__ P, const float* __restrict__ Q,
    const float* __restrict__ Rt, const float* __restrict__ T,
    const float* __restrict__ normp, const float* __restrict__ w,
    const float* __restrict__ Wp, float* __restrict__ out) {
    int h = blockIdx.y;
    int i0 = blockIdx.x * 4;
    size_t hb = (size_t)h * 65536;
    __shared__ float rn_s[256];
    __shared__ __align__(16) float qs[1024];   // [4][256] = Q*rn
    __shared__ __align__(16) float Ss[1024];   // [4][256] = S rows
    __shared__ __align__(16) float wp[1024];   // [4][256]; later redx[512]
    __shared__ __align__(16) float wq[1024];   // [4][256]; later redy[512]
    __shared__ __align__(16) float vT[8320];   // red[8][4][256] / vT[32][260] / Wps[32][128]
    __shared__ float ys[144];                  // [4][33+]
    int t = threadIdx.x;
    if (t < 256) {
        float s = 0.f;
#pragma unroll
        for (int ib = 0; ib < 16; ib++) s += normp[h * 4096 + ib * 256 + t];
        rn_s[t] = 1.f / fmaxf(s, 1e-6f);
    }
    __syncthreads();
    if (t < 256) {   // qs = Q rows * rn
        int row = t >> 6, jqc = (t & 63) * 4;
        float4 q4 = *(const float4*)&Q[hb + (size_t)(i0 + row) * 256 + jqc];
        float4 rn4 = *(float4*)&rn_s[jqc];
        q4.x *= rn4.x; q4.y *= rn4.y; q4.z *= rn4.z; q4.w *= rn4.w;
        *(float4*)&qs[row * 256 + jqc] = q4;
    }
    __syncthreads();
    // S partials: thread (jqc = (t&63)*4, kq = t>>6 in 0..7) does 32 k-rows
    {
        int jqc = (t & 63) * 4, kq = t >> 6;
        float4 acc0 = {0, 0, 0, 0}, acc1 = {0, 0, 0, 0};
        float4 acc2 = {0, 0, 0, 0}, acc3 = {0, 0, 0, 0};
#pragma unroll 8
        for (int kk = 0; kk < 32; kk++) {
            int k = kq * 32 + kk;
            float4 r4 = *(const float4*)&Rt[hb + (size_t)k * 256 + jqc];
            float q0 = qs[0 * 256 + k], q1 = qs[1 * 256 + k];
            float q2 = qs[2 * 256 + k], q3 = qs[3 * 256 + k];
            acc0.x += q0 * r4.x; acc0.y += q0 * r4.y; acc0.z += q0 * r4.z; acc0.w += q0 * r4.w;
            acc1.x += q1 * r4.x; acc1.y += q1 * r4.y; acc1.z += q1 * r4.z; acc1.w += q1 * r4.w;
            acc2.x += q2 * r4.x; acc2.y += q2 * r4.y; acc2.z += q2 * r4.z; acc2.w += q2 * r4.w;
            acc3.x += q3 * r4.x; acc3.y += q3 * r4.y; acc3.z += q3 * r4.z; acc3.w += q3 * r4.w;
        }
        float* red = vT;  // red[kq][row][j]: 8*4*256 = 8192 floats
        *(float4*)&red[(kq * 4 + 0) * 256 + jqc] = acc0;
        *(float4*)&red[(kq * 4 + 1) * 256 + jqc] = acc1;
        *(float4*)&red[(kq * 4 + 2) * 256 + jqc] = acc2;
        *(float4*)&red[(kq * 4 + 3) * 256 + jqc] = acc3;
    }
    __syncthreads();
    if (t < 256) {   // reduce 8 k-groups -> Ss
        int row = t >> 6, jqc = (t & 63) * 4;
        float* red = vT;
        float4 sm = {0, 0, 0, 0};
#pragma unroll
        for (int g8 = 0; g8 < 8; g8++) {
            float4 s4 = *(float4*)&red[(g8 * 4 + row) * 256 + jqc];
            sm.x += s4.x; sm.y += s4.y; sm.z += s4.z; sm.w += s4.w;
        }
        *(float4*)&Ss[row * 256 + jqc] = sm;
    }
    __syncthreads();  // red no longer needed; vT region free
#pragma unroll
    for (int m = 0; m < 4; m++) {  // stage vT[d][j] (transposed), 512 threads
        int jj = m * 64 + (t >> 3);
        int dd = (t & 7) * 4;
        float4 v4 = *(const float4*)&w[(size_t)jj * 512 + 384 + h * 32 + dd];
        vT[(dd + 0) * 260 + jj] = v4.x;
        vT[(dd + 1) * 260 + jj] = v4.y;
        vT[(dd + 2) * 260 + jj] = v4.z;
        vT[(dd + 3) * 260 + jj] = v4.w;
    }
    {   // wp = P .* S ; wq = qs .* (T0+T1) — 512 threads, float2 each
        int rr = t >> 7, jj = (t & 127) * 2;
        size_t o = hb + (size_t)(i0 + rr) * 256 + jj;
        float2 p2  = *(const float2*)&P[o];
        float2 t2a = *(const float2*)&T[o];
        float2 t2b = *(const float2*)&T[o + 262144];
        float2 q2  = *(float2*)&qs[rr * 256 + jj];
        float2 s2  = *(float2*)&Ss[rr * 256 + jj];
        float2 wpv, wqv;
        wpv.x = p2.x * s2.x; wpv.y = p2.y * s2.y;
        wqv.x = q2.x * (t2a.x + t2b.x); wqv.y = q2.y * (t2a.y + t2b.y);
        *(float2*)&wp[rr * 256 + jj] = wpv;
        *(float2*)&wq[rr * 256 + jj] = wqv;
    }
    __syncthreads();
    // x1x2 main: (d = t&31, rl = (t>>5)&3, jg = t>>7 in 0..3) quarter j-range
    int d = t & 31, rl = (t >> 5) & 3, jg = t >> 7;
    {
        int jbase = jg * 64;
        float x1 = 0.f, x2 = 0.f;
#pragma unroll 8
        for (int q = 0; q < 16; q++) {
            int j = jbase + 4 * q;
            float4 wp4 = *(float4*)&wp[rl * 256 + j];
            float4 wq4 = *(float4*)&wq[rl * 256 + j];
            float4 v4  = *(float4*)&vT[d * 260 + j];
            x1 += wp4.x * v4.x + wp4.y * v4.y + wp4.z * v4.z + wp4.w * v4.w;
            x2 += wq4.x * v4.x + wq4.y * v4.y + wq4.z * v4.z + wq4.w * v4.w;
        }
        __syncthreads();  // done reading wp/wq/vT
        wp[t] = x1;       // redx
        wq[t] = x2;       // redy
    }
    float* Wps = vT;  // [32][128]
#pragma unroll
    for (int m = 0; m < 2; m++) {
        int idx = m * 512 + t;
        int k = idx >> 5, n = (idx & 31) * 4;
        *(float4*)&Wps[k * 128 + n] = *(const float4*)&Wp[(size_t)(h * 32 + k) * 128 + n];
    }
    __syncthreads();
    if (t < 128) {
        float x1t = (wp[t] + wp[t + 128]) + (wp[t + 256] + wp[t + 384]);
        float x2t = (wq[t] + wq[t + 128]) + (wq[t + 256] + wq[t + 384]);
        ys[rl * 33 + d] = x1t * x2t;   // for t<128: rl = (t>>5)&3, d = t&31
    }
    __syncthreads();
    {   // projection: 512 threads, one row each
        int n = t & 127, row = t >> 7;
        float acc = 0.f;
#pragma unroll
        for (int k = 0; k < 32; k++) acc += ys[row * 33 + k] * Wps[k * 128 + n];
        atomicAdd(&out[(size_t)(i0 + row) * 128 + n], acc);
    }
}

extern "C" void kernel_launch(void* const* d_in, const int* in_sizes, int n_in,
                              void* d_out, int out_size, void* d_ws, size_t ws_size,
                              hipStream_t stream) {
    const float* x      = (const float*)d_in[0];
    const float* W_w    = (const float*)d_in[1];
    const float* W_proj = (const float*)d_in[2];
    const float* b_proj = (const float*)d_in[3];
    float* out = (float*)d_out;
    float* ws  = (float*)d_ws;

    float* w     = ws + OFF_W;
    float* P     = ws + OFF_P;
    float* Q     = ws + OFF_Q;
    float* Rt    = ws + OFF_RT;
    float* T     = ws + OFF_T;
    float* normp = ws + OFF_NORMP;

    k_w<<<dim3(16, 8), 256, 0, stream>>>(x, W_w, w, b_proj, out);
    k_T<<<dim3(8, 8, 8), 256, 0, stream>>>(w, P, Q, Rt, T, normp);
    k_x1x2S<<<dim3(64, 4), 512, 0, stream>>>(P, Q, Rt, T, normp, w, W_proj, out);
}